// Round 11
// baseline (717.595 us; speedup 1.0000x reference)
//
#include <hip/hip_runtime.h>

typedef unsigned short u16;
typedef short bf16x8 __attribute__((ext_vector_type(8)));
typedef u16 u16x8 __attribute__((ext_vector_type(8)));
typedef float f32x4 __attribute__((ext_vector_type(4)));

__device__ __forceinline__ float bf2f(u16 u) {
    union { unsigned u; float f; } c; c.u = ((unsigned)u) << 16; return c.f;
}
__device__ __forceinline__ u16 f2bf(float f) {
    union { float f; unsigned u; } c; c.f = f;
    unsigned r = c.u + 0x7FFFu + ((c.u >> 16) & 1u);
    return (u16)(r >> 16);
}
__device__ __forceinline__ float tanh_fast(float x) {
    float e = __expf(2.0f * x);
    return 1.0f - 2.0f / (e + 1.0f);
}
__device__ __forceinline__ void gll16(const void* g, void* l) {
    __builtin_amdgcn_global_load_lds((const __attribute__((address_space(1))) void*)g,
                                     (__attribute__((address_space(3))) void*)l, 16, 0, 0);
}

#define BAR() __builtin_amdgcn_s_barrier()

// ---------------- f32 -> bf16 convert, 8 elems/thread ----------------
__global__ __launch_bounds__(256) void cvt_f32_bf16(const float* __restrict__ src,
                                                    u16* __restrict__ dst, int n8) {
    int i = blockIdx.x * blockDim.x + threadIdx.x;
    int stride = gridDim.x * blockDim.x;
    for (; i < n8; i += stride) {
        const float4* s = (const float4*)(src + (size_t)i * 8);
        float4 a = s[0], b = s[1];
        u16x8 o;
        o[0] = f2bf(a.x); o[1] = f2bf(a.y); o[2] = f2bf(a.z); o[3] = f2bf(a.w);
        o[4] = f2bf(b.x); o[5] = f2bf(b.y); o[6] = f2bf(b.z); o[7] = f2bf(b.w);
        *(u16x8*)(dst + (size_t)i * 8) = o;
    }
}

// ---------------- mq = tanh(Wm @ m_q + bm), one wave per output ----------------
__global__ __launch_bounds__(256) void mq_kernel(const float* __restrict__ Wm,
                                                 const float* __restrict__ q,
                                                 const float* __restrict__ bm,
                                                 float* __restrict__ mq, int D) {
    int w = threadIdx.x >> 6, l = threadIdx.x & 63;
    int e = blockIdx.x * 4 + w;
    const float* wp = Wm + (size_t)e * D;
    float s = 0.f;
    for (int j = 0; j < D; j += 256) {
        float4 wv = *(const float4*)(wp + j + l * 4);
        float4 qv = *(const float4*)(q + j + l * 4);
        s += wv.x * qv.x + wv.y * qv.y + wv.z * qv.z + wv.w * qv.w;
    }
    #pragma unroll
    for (int o = 32; o >= 1; o >>= 1) s += __shfl_xor(s, o);
    if (l == 0) mq[e] = tanh_fast(s + bm[e]);
}

// ---------------- GEMM1: Sg = bf16( tanh(hbf@Wq^T + bq) * mq )  (r9 structure) ----------------
__global__ __launch_bounds__(512, 2) void gemm8(const u16* __restrict__ A,
                                                const u16* __restrict__ B,
                                                const float* __restrict__ bias,
                                                const float* __restrict__ gate,
                                                u16* __restrict__ C,
                                                int M, int N, int K) {
    __shared__ u16 sh[65536];
    char* LDS = (char*)sh;
    const int K2 = K * 2;
    const int KT = K >> 6;

    const int tid = threadIdx.x;
    const int w = tid >> 6, l = tid & 63;
    const int wm = w >> 2, wn = w & 3;

    int orig = blockIdx.x + gridDim.x * blockIdx.y;
    int nwg = gridDim.x * gridDim.y;
    int id = ((nwg & 7) == 0) ? ((orig & 7) * (nwg >> 3) + (orig >> 3)) : orig;
    const int tileN = (id % gridDim.x) * 256;
    const int tileM = (id / gridDim.x) * 256;

    const int r0 = (w * 2) * 8 + (l >> 3);
    const int r1 = (w * 2 + 1) * 8 + (l >> 3);
    const int cc = ((l & 7) ^ (l >> 3)) << 4;
    const char* srcA0 = (const char*)A + (size_t)(tileM + r0) * K2 + cc;
    const char* srcA1 = (const char*)A + (size_t)(tileM + r1) * K2 + cc;
    const char* srcB0 = (const char*)B + (size_t)(tileN + r0) * K2 + cc;
    const char* srcB1 = (const char*)B + (size_t)(tileN + r1) * K2 + cc;
    const int ldc0 = (w * 2) * 1024, ldc1 = (w * 2 + 1) * 1024;

#define STG_A(tk, h) do { size_t go = (size_t)(tk) * 128 + (size_t)(h) * 128 * K2; \
    int sb = ((((tk) & 1) * 2 + (h)) * 16384); \
    gll16(srcA0 + go, LDS + sb + ldc0); gll16(srcA1 + go, LDS + sb + ldc1); } while (0)
#define STG_B(tk, h) do { size_t go = (size_t)(tk) * 128 + (size_t)(h) * 128 * K2; \
    int sb = 65536 + ((((tk) & 1) * 2 + (h)) * 16384); \
    gll16(srcB0 + go, LDS + sb + ldc0); gll16(srcB1 + go, LDS + sb + ldc1); } while (0)

    const int sw = l & 7;
    const int rowA = (wm * 64 + (l & 15)) * 128;
    const int rowB = (wn * 32 + (l & 15)) * 128;
    const int ck0 = (((l >> 4) ^ sw) << 4);
    const int ck1 = (((4 + (l >> 4)) ^ sw) << 4);
    const char* pA0 = LDS + rowA + ck0;
    const char* pA1 = LDS + rowA + ck1;
    const char* pB0 = LDS + 65536 + rowB + ck0;
    const char* pB1 = LDS + 65536 + rowB + ck1;

    f32x4 acc[2][4][2][2] = {};

    STG_A(0, 0); STG_B(0, 0); STG_A(0, 1); STG_B(0, 1);
    STG_A(1, 0); STG_B(1, 0);
    asm volatile("s_waitcnt vmcnt(4)" ::: "memory");
    BAR();

#define MFMA_CLUSTER(QM, QN, AF, BF)                                            \
    __builtin_amdgcn_s_setprio(1);                                              \
    _Pragma("unroll")                                                           \
    for (int fm = 0; fm < 4; ++fm)                                              \
        _Pragma("unroll")                                                       \
        for (int fn = 0; fn < 2; ++fn) {                                        \
            acc[QM][fm][QN][fn] = __builtin_amdgcn_mfma_f32_16x16x32_bf16(      \
                AF[fm][0], BF[fn][0], acc[QM][fm][QN][fn], 0, 0, 0);            \
            acc[QM][fm][QN][fn] = __builtin_amdgcn_mfma_f32_16x16x32_bf16(      \
                AF[fm][1], BF[fn][1], acc[QM][fm][QN][fn], 0, 0, 0);            \
        }                                                                       \
    __builtin_amdgcn_s_setprio(0);

#define ITER(t, P) do {                                                         \
    constexpr int A0O = (2 * (P)) * 16384;                                      \
    constexpr int A1O = (2 * (P) + 1) * 16384;                                  \
    bf16x8 af[4][2], b0[2][2], b1[2][2];                                        \
    _Pragma("unroll")                                                           \
    for (int fm = 0; fm < 4; ++fm) {                                            \
        af[fm][0] = *(const bf16x8*)(pA0 + A0O + fm * 2048);                    \
        af[fm][1] = *(const bf16x8*)(pA1 + A0O + fm * 2048);                    \
    }                                                                           \
    _Pragma("unroll")                                                           \
    for (int fn = 0; fn < 2; ++fn) {                                            \
        b0[fn][0] = *(const bf16x8*)(pB0 + A0O + fn * 2048);                    \
        b0[fn][1] = *(const bf16x8*)(pB1 + A0O + fn * 2048);                    \
    }                                                                           \
    if ((t) + 1 < KT) STG_A((t) + 1, 1);                                        \
    BAR();                                                                      \
    MFMA_CLUSTER(0, 0, af, b0)                                                  \
    BAR();                                                                      \
    _Pragma("unroll")                                                           \
    for (int fn = 0; fn < 2; ++fn) {                                            \
        b1[fn][0] = *(const bf16x8*)(pB0 + A1O + fn * 2048);                    \
        b1[fn][1] = *(const bf16x8*)(pB1 + A1O + fn * 2048);                    \
    }                                                                           \
    if ((t) + 1 < KT) STG_B((t) + 1, 1);                                        \
    BAR();                                                                      \
    MFMA_CLUSTER(0, 1, af, b1)                                                  \
    BAR();                                                                      \
    _Pragma("unroll")                                                           \
    for (int fm = 0; fm < 4; ++fm) {                                            \
        af[fm][0] = *(const bf16x8*)(pA0 + A1O + fm * 2048);                    \
        af[fm][1] = *(const bf16x8*)(pA1 + A1O + fm * 2048);                    \
    }                                                                           \
    if ((t) + 2 < KT) STG_A((t) + 2, 0);                                        \
    BAR();                                                                      \
    MFMA_CLUSTER(1, 0, af, b0)                                                  \
    BAR();                                                                      \
    if ((t) + 2 < KT) STG_B((t) + 2, 0);                                        \
    BAR();                                                                      \
    MFMA_CLUSTER(1, 1, af, b1)                                                  \
    if ((t) + 2 < KT) asm volatile("s_waitcnt vmcnt(4)" ::: "memory");          \
    else              asm volatile("s_waitcnt vmcnt(0)" ::: "memory");          \
    BAR();                                                                      \
} while (0)

    for (int tt = 0; tt < KT; tt += 2) {
        ITER(tt, 0);
        ITER(tt + 1, 1);
    }
#undef ITER
#undef MFMA_CLUSTER
#undef STG_A
#undef STG_B

    const int cr = (l >> 4) * 4;
    const int cl = l & 15;
    #pragma unroll
    for (int qn = 0; qn < 2; ++qn)
        #pragma unroll
        for (int fn = 0; fn < 2; ++fn) {
            const int col = tileN + qn * 128 + wn * 32 + fn * 16 + cl;
            const float bs = bias[col];
            const float gt = gate[col];
            #pragma unroll
            for (int qm = 0; qm < 2; ++qm)
                #pragma unroll
                for (int fm = 0; fm < 4; ++fm)
                    #pragma unroll
                    for (int r = 0; r < 4; ++r) {
                        const int row = tileM + qm * 128 + wm * 64 + fm * 16 + cr + r;
                        float v = tanh_fast(acc[qm][fm][qn][fn][r] + bs) * gt;
                        C[(size_t)row * N + col] = f2bf(v);
                    }
        }
}

// ---- Fused GEMM2 + online softmax + weighted sum + m_q_new ----
// Block = 128 rows (grid 256 = 1/CU). 8 waves (2M x 4N, 64x64/wave). N-outer loop
// of 8 x 256-col tiles; per tile: K-loop (BK=64, 2 LDS slots, 3-bit XOR swizzle,
// lgkm0-sealed write-after-read, vmcnt(6) ledger), then online-softmax epilogue:
// logits = acc + ba; row-max via in-lane fn-reduce + 16-lane shfl + cross-wave LDS;
// running (m, den, num=Σe·hbf) state in LDS; final out = num/den, m_q_new = m_q + out.
__global__ __launch_bounds__(512, 2) void gemm_sm(const u16* __restrict__ A,   // Sg [M,K]
                                                  const u16* __restrict__ B,   // Wa [N,K]
                                                  const float* __restrict__ bias,
                                                  const u16* __restrict__ H,   // hbf [M,N]
                                                  const float* __restrict__ m_q,
                                                  float* __restrict__ out,
                                                  int M, int N, int K) {
    __shared__ u16 sh[53248];            // 106496 B: A 2x16K @0 | B 2x32K @32768 | scratch @98304
    char* LDS = (char*)sh;
    const int K2 = K * 2;
    const int KT = K >> 6;               // 32
    const int tid = threadIdx.x;
    const int w = tid >> 6, l = tid & 63;
    const int wm = w >> 2, wn = w & 3;

    int orig = blockIdx.x;
    int nwg = gridDim.x;                 // 256, divisible by 8
    int id = ((nwg & 7) == 0) ? ((orig & 7) * (nwg >> 3) + (orig >> 3)) : orig;
    const int r0g = id * 128;

    float* redmax = (float*)(LDS + 98304);           // [128][4]
    float* redd   = (float*)(LDS + 98304 + 2048);    // [128][4]
    float* redn   = (float*)(LDS + 98304 + 4096);    // [128][4]
    float* m_s    = (float*)(LDS + 98304 + 6144);    // [128]
    float* d_s    = (float*)(LDS + 98304 + 6656);    // [128]
    float* n_s    = (float*)(LDS + 98304 + 7168);    // [128]
    float* mrow   = (float*)(LDS + 98304 + 7680);    // [128]

    // staging geometry (3-bit swizzle, pre-swizzled global source)
    const int ra = l >> 3;
    const int cc = ((l & 7) ^ ra) << 4;
    const char* sA = (const char*)A + (size_t)(r0g + w * 16 + ra) * K2 + cc;  // rows +0,+8
    const char* sBb = (const char*)B + (size_t)(w * 32 + ra) * K2 + cc;       // + nt*256*K2; rows +0,8,16,24
    char* dA = LDS + w * 2048;           // + slot*16384 ; +0,+1024
    char* dB = LDS + 32768 + w * 4096;   // + slot*32768 ; +0..+3072

    // reader bases
    const int sw = l & 7;
    const int ck0 = (((l >> 4) ^ sw) << 4);
    const int ck1 = (((4 + (l >> 4)) ^ sw) << 4);
    const char* pA0 = LDS + (wm * 64 + (l & 15)) * 128 + ck0;
    const char* pA1 = LDS + (wm * 64 + (l & 15)) * 128 + ck1;
    const char* pB0 = LDS + 32768 + (wn * 64 + (l & 15)) * 128 + ck0;
    const char* pB1 = LDS + 32768 + (wn * 64 + (l & 15)) * 128 + ck1;

    const int cr = (l >> 4) * 4;
    const int cl = l & 15;

    if (tid < 128) { m_s[tid] = -1e30f; d_s[tid] = 0.f; n_s[tid] = 0.f; }
    BAR();

    for (int nt = 0; nt < 8; ++nt) {
        const int n0 = nt * 256;
        const char* sB = sBb + (size_t)n0 * K2;

#define STG(tk, SLA, SLB) do { size_t go = (size_t)(tk) * 128;                  \
    gll16(sA + go, dA + (SLA)); gll16(sA + go + (size_t)8 * K2, dA + (SLA) + 1024); \
    gll16(sB + go, dB + (SLB)); gll16(sB + go + (size_t)8 * K2, dB + (SLB) + 1024); \
    gll16(sB + go + (size_t)16 * K2, dB + (SLB) + 2048);                        \
    gll16(sB + go + (size_t)24 * K2, dB + (SLB) + 3072); } while (0)

        f32x4 acc[4][4] = {};

        STG(0, 0, 0); STG(1, 16384, 32768);
        asm volatile("s_waitcnt vmcnt(6)" ::: "memory");
        BAR();

#define IT(t, P) do {                                                           \
    constexpr int SA = (P) * 16384;                                             \
    constexpr int SB = (P) * 32768;                                             \
    bf16x8 af[4][2], bf[4][2];                                                  \
    _Pragma("unroll")                                                           \
    for (int fm = 0; fm < 4; ++fm) {                                            \
        af[fm][0] = *(const bf16x8*)(pA0 + SA + fm * 2048);                     \
        af[fm][1] = *(const bf16x8*)(pA1 + SA + fm * 2048);                     \
    }                                                                           \
    _Pragma("unroll")                                                           \
    for (int fn = 0; fn < 4; ++fn) {                                            \
        bf[fn][0] = *(const bf16x8*)(pB0 + SB + fn * 2048);                     \
        bf[fn][1] = *(const bf16x8*)(pB1 + SB + fn * 2048);                     \
    }                                                                           \
    asm volatile("s_waitcnt lgkmcnt(0)" ::: "memory");                          \
    BAR();                                                                      \
    if ((t) + 2 < KT) STG((t) + 2, SA, SB);                                     \
    __builtin_amdgcn_s_setprio(1);                                              \
    _Pragma("unroll")                                                           \
    for (int fm = 0; fm < 4; ++fm)                                              \
        _Pragma("unroll")                                                       \
        for (int fn = 0; fn < 4; ++fn) {                                        \
            acc[fm][fn] = __builtin_amdgcn_mfma_f32_16x16x32_bf16(              \
                af[fm][0], bf[fn][0], acc[fm][fn], 0, 0, 0);                    \
            acc[fm][fn] = __builtin_amdgcn_mfma_f32_16x16x32_bf16(              \
                af[fm][1], bf[fn][1], acc[fm][fn], 0, 0, 0);                    \
        }                                                                       \
    __builtin_amdgcn_s_setprio(0);                                              \
    if ((t) + 2 < KT)      asm volatile("s_waitcnt vmcnt(6)" ::: "memory");     \
    else if ((t) + 1 < KT) asm volatile("s_waitcnt vmcnt(0)" ::: "memory");     \
    BAR();                                                                      \
} while (0)

        for (int tt = 0; tt < KT; tt += 2) {
            IT(tt, 0);
            IT(tt + 1, 1);
        }
#undef IT
#undef STG

        // ---- online softmax epilogue for this N-tile ----
        float bs[4];
        #pragma unroll
        for (int fn = 0; fn < 4; ++fn) bs[fn] = bias[n0 + wn * 64 + fn * 16 + cl];

        float tmax[4][4];
        #pragma unroll
        for (int fm = 0; fm < 4; ++fm)
            #pragma unroll
            for (int rr = 0; rr < 4; ++rr) {
                float v = acc[fm][0][rr] + bs[0];
                #pragma unroll
                for (int fn = 1; fn < 4; ++fn) v = fmaxf(v, acc[fm][fn][rr] + bs[fn]);
                tmax[fm][rr] = v;
            }
        #pragma unroll
        for (int o = 8; o >= 1; o >>= 1)
            #pragma unroll
            for (int fm = 0; fm < 4; ++fm)
                #pragma unroll
                for (int rr = 0; rr < 4; ++rr)
                    tmax[fm][rr] = fmaxf(tmax[fm][rr], __shfl_xor(tmax[fm][rr], o));
        if (cl == 0) {
            #pragma unroll
            for (int fm = 0; fm < 4; ++fm)
                #pragma unroll
                for (int rr = 0; rr < 4; ++rr)
                    redmax[(wm * 64 + fm * 16 + cr + rr) * 4 + wn] = tmax[fm][rr];
        }
        BAR();
        if (tid < 128) {
            float mt = fmaxf(fmaxf(redmax[tid * 4], redmax[tid * 4 + 1]),
                             fmaxf(redmax[tid * 4 + 2], redmax[tid * 4 + 3]));
            float mo = m_s[tid];
            float mn = fmaxf(mo, mt);
            float sc = __expf(mo - mn);
            d_s[tid] *= sc; n_s[tid] *= sc; m_s[tid] = mn; mrow[tid] = mn;
        }
        BAR();

        float dsum[4][4], nsum[4][4];
        #pragma unroll
        for (int fm = 0; fm < 4; ++fm)
            #pragma unroll
            for (int rr = 0; rr < 4; ++rr) {
                const int rl = wm * 64 + fm * 16 + cr + rr;
                const float mm = mrow[rl];
                const u16* hp = H + (size_t)(r0g + rl) * N + n0 + wn * 64 + cl;
                float ds = 0.f, ns = 0.f;
                #pragma unroll
                for (int fn = 0; fn < 4; ++fn) {
                    float e = __expf(acc[fm][fn][rr] + bs[fn] - mm);
                    ds += e;
                    ns += e * bf2f(hp[fn * 16]);
                }
                dsum[fm][rr] = ds; nsum[fm][rr] = ns;
            }
        #pragma unroll
        for (int o = 8; o >= 1; o >>= 1)
            #pragma unroll
            for (int fm = 0; fm < 4; ++fm)
                #pragma unroll
                for (int rr = 0; rr < 4; ++rr) {
                    dsum[fm][rr] += __shfl_xor(dsum[fm][rr], o);
                    nsum[fm][rr] += __shfl_xor(nsum[fm][rr], o);
                }
        if (cl == 0) {
            #pragma unroll
            for (int fm = 0; fm < 4; ++fm)
                #pragma unroll
                for (int rr = 0; rr < 4; ++rr) {
                    const int rl = wm * 64 + fm * 16 + cr + rr;
                    redd[rl * 4 + wn] = dsum[fm][rr];
                    redn[rl * 4 + wn] = nsum[fm][rr];
                }
        }
        BAR();
        if (tid < 128) {
            d_s[tid] += redd[tid * 4] + redd[tid * 4 + 1] + redd[tid * 4 + 2] + redd[tid * 4 + 3];
            n_s[tid] += redn[tid * 4] + redn[tid * 4 + 1] + redn[tid * 4 + 2] + redn[tid * 4 + 3];
        }
        BAR();
    }

    if (tid < 128) {
        const int rg = r0g + tid;
        float o = n_s[tid] / d_s[tid];
        out[rg] = o;
        out[M + rg] = m_q[rg & (N - 1)] + o;
    }
}

extern "C" void kernel_launch(void* const* d_in, const int* in_sizes, int n_in,
                              void* d_out, int out_size, void* d_ws, size_t ws_size,
                              hipStream_t stream) {
    const float* hidden = (const float*)d_in[0];
    const float* m_q    = (const float*)d_in[1];
    const float* Wq     = (const float*)d_in[2];
    const float* bq     = (const float*)d_in[3];
    const float* Wm     = (const float*)d_in[4];
    const float* bm     = (const float*)d_in[5];
    const float* Wa     = (const float*)d_in[6];
    const float* ba     = (const float*)d_in[7];
    float* out = (float*)d_out;

    const int D = 2048;
    const int M = 16 * 2048;  // B*S = 32768

    char* ws = (char*)d_ws;
    size_t oH  = 0;
    size_t oS  = oH  + (size_t)M * D * 2;   // Sg bf16
    size_t oWq = oS  + (size_t)M * D * 2;
    size_t oWa = oWq + (size_t)D * D * 2;
    size_t oMq = oWa + (size_t)D * D * 2;
    size_t need = oMq + (size_t)D * sizeof(float);
    if (ws_size < need) return;

    u16* hbf    = (u16*)(ws + oH);
    u16* Sg     = (u16*)(ws + oS);
    u16* Wqb    = (u16*)(ws + oWq);
    u16* Wab    = (u16*)(ws + oWa);
    float* mq   = (float*)(ws + oMq);

    cvt_f32_bf16<<<4096, 256, 0, stream>>>(hidden, hbf, M * D / 8);
    cvt_f32_bf16<<<1024, 256, 0, stream>>>(Wq, Wqb, D * D / 8);
    cvt_f32_bf16<<<1024, 256, 0, stream>>>(Wa, Wab, D * D / 8);
    mq_kernel<<<D / 4, 256, 0, stream>>>(Wm, m_q, bm, mq, D);

    dim3 grid(D / 256, M / 256);  // (8, 128)
    gemm8<<<grid, 512, 0, stream>>>(hbf, Wqb, bq, mq, Sg, M, D, D);

    gemm_sm<<<M / 128, 512, 0, stream>>>(Sg, Wab, ba, hbf, m_q, out, M, D, D);
}